// Round 4
// baseline (285.164 us; speedup 1.0000x reference)
//
#include <hip/hip_runtime.h>
#include <hip/hip_bf16.h>

// Problem constants (fixed by setup_inputs): Na=Nb=200000, Da=Db=64, S=256.
#define NKEYS   (1 << 24)          // 256^3 possible locations
#define NW      (NKEYS / 32)       // 524288 32-bit presence words (2 MB)
#define TPB     256
#define SCAN_BLOCKS 512            // NW / (TPB*4)
#define MAXN    400000             // Na + Nb

typedef float  f32x4 __attribute__((ext_vector_type(4)));   // native vector: ok for nontemporal builtins
typedef unsigned int u32x4 __attribute__((ext_vector_type(4)));

// Device-global scratch. Re-initialized every call (deterministic).
__device__ unsigned int        g_bits[NW];        // presence bitmask per key
__device__ unsigned int        g_wordPrefix[NW];  // exclusive rank base per 32-key word
__device__ unsigned long long  g_tileStatus[SCAN_BLOCKS]; // hi32: 0=inv,1=agg,2=incl; lo32: value
__device__ unsigned int        g_tileCounter;
__device__ int                 g_winner_a[MAXN];  // per-unique-slot winning a-row (max index)
__device__ int                 g_winner_b[MAXN];  // per-unique-slot winning b-row (max index)

// ---------------------------------------------------------------- fused init
__global__ void k_init(float* out_loc, int N) {
    int i = blockIdx.x * blockDim.x + threadIdx.x;          // 3N threads
    if (i < NW / 4) reinterpret_cast<u32x4*>(g_bits)[i] = (u32x4)(0u);
    if (i < N) { g_winner_a[i] = -1; g_winner_b[i] = -1; }
    if (i < N * 3) out_loc[i] = -1.0f;                      // fill_value=-1 padding rows
    if (i < SCAN_BLOCKS) g_tileStatus[i] = 0ull;
    if (i == 0) g_tileCounter = 0u;
}

// ---------------------------------------------------------------- mark presence bits
__global__ void k_mark(const int* __restrict__ a_loc, const int* __restrict__ b_loc,
                       int Na, int N) {
    int i = blockIdx.x * blockDim.x + threadIdx.x;
    if (i >= N) return;
    const int* p = (i < Na) ? (a_loc + (size_t)i * 3) : (b_loc + (size_t)(i - Na) * 3);
    int key = (p[0] << 16) | (p[1] << 8) | p[2];
    atomicOr(&g_bits[key >> 5], 1u << (key & 31));
}

// ---------------------------------------------------------------- single-pass scan (decoupled lookback)
// Replaces reduce+scan+prefix: reads g_bits once, writes g_wordPrefix and the
// sorted unique locations. Dynamic tile-id guarantees lookback progress even
// without full-grid residency; tile status goes through device-scope atomics
// (per-XCD L2s are not coherent).
__global__ void k_scan_fused(float* __restrict__ out_loc) {
    __shared__ unsigned int s[TPB];
    __shared__ unsigned int sTile;
    __shared__ unsigned int sPrefix;
    int t = threadIdx.x;
    if (t == 0) sTile = atomicAdd(&g_tileCounter, 1u);
    __syncthreads();
    unsigned int tile = sTile;

    u32x4 wv = reinterpret_cast<const u32x4*>(g_bits)[tile * TPB + t];
    unsigned int wlocal[4] = { wv.x, wv.y, wv.z, wv.w };
    unsigned int cnt = __popc(wv.x) + __popc(wv.y) + __popc(wv.z) + __popc(wv.w);
    s[t] = cnt;
    __syncthreads();
    for (int off = 1; off < TPB; off <<= 1) {
        unsigned int u = (t >= off) ? s[t - off] : 0u;
        __syncthreads();
        s[t] += u;
        __syncthreads();
    }
    unsigned int total = s[TPB - 1];

    if (t == 0) {
        // publish: tile 0 can publish inclusive immediately
        unsigned long long pkt = ((unsigned long long)((tile == 0) ? 2u : 1u) << 32) | total;
        __hip_atomic_store(&g_tileStatus[tile], pkt, __ATOMIC_RELEASE, __HIP_MEMORY_SCOPE_AGENT);
        unsigned int excl = 0u;
        if (tile > 0) {
            int p = (int)tile - 1;
            while (true) {
                unsigned long long v = __hip_atomic_load(&g_tileStatus[p], __ATOMIC_ACQUIRE,
                                                         __HIP_MEMORY_SCOPE_AGENT);
                unsigned int st = (unsigned int)(v >> 32);
                if (st == 0u) { __builtin_amdgcn_s_sleep(1); continue; }
                excl += (unsigned int)v;
                if (st == 2u) break;
                --p;
            }
            __hip_atomic_store(&g_tileStatus[tile],
                               ((unsigned long long)2u << 32) | (excl + total),
                               __ATOMIC_RELEASE, __HIP_MEMORY_SCOPE_AGENT);
        }
        sPrefix = excl;
    }
    __syncthreads();

    unsigned int r = sPrefix + s[t] - cnt;                  // exclusive rank for first word
    int w0 = (int)(tile * TPB + t) * 4;
#pragma unroll
    for (int j = 0; j < 4; ++j) {
        unsigned int bits = wlocal[j];
        g_wordPrefix[w0 + j] = r;
        while (bits) {
            int bit = __ffs(bits) - 1;
            bits &= bits - 1;
            int key = ((w0 + j) << 5) | bit;
            float* p = out_loc + (size_t)r * 3;
            p[0] = (float)(key >> 16);
            p[1] = (float)((key >> 8) & 255);
            p[2] = (float)(key & 255);
            ++r;
        }
    }
}

// ---------------------------------------------------------------- inverse indices + winner selection
__global__ void k_reverse(const int* __restrict__ a_loc, const int* __restrict__ b_loc,
                          int Na, int N) {
    int i = blockIdx.x * blockDim.x + threadIdx.x;
    if (i >= N) return;
    const int* p = (i < Na) ? (a_loc + (size_t)i * 3) : (b_loc + (size_t)(i - Na) * 3);
    int key = (p[0] << 16) | (p[1] << 8) | p[2];
    unsigned int word = g_bits[key >> 5];
    unsigned int r = g_wordPrefix[key >> 5] + __popc(word & ((1u << (key & 31)) - 1u));
    if (i < Na) atomicMax(&g_winner_a[r], i);               // last (max) row index wins,
    else        atomicMax(&g_winner_b[r], i - Na);          // matching XLA CPU scatter order
}

// ---------------------------------------------------------------- gather features (nt: use-once streams)
__global__ void k_gather(const float* __restrict__ a_feat, const float* __restrict__ b_feat,
                         float* __restrict__ out_feat, int N) {
    int idx = blockIdx.x * blockDim.x + threadIdx.x;        // N*32 threads, float4 each
    if (idx >= N * 32) return;
    int u  = idx >> 5;
    int c4 = (idx & 31) * 4;
    f32x4 v = (f32x4)(0.f);
    if (c4 < 64) {
        int w = g_winner_a[u];
        if (w >= 0) v = __builtin_nontemporal_load(
                            reinterpret_cast<const f32x4*>(a_feat + (size_t)w * 64 + c4));
    } else {
        int w = g_winner_b[u];
        if (w >= 0) v = __builtin_nontemporal_load(
                            reinterpret_cast<const f32x4*>(b_feat + (size_t)w * 64 + (c4 - 64)));
    }
    __builtin_nontemporal_store(v, reinterpret_cast<f32x4*>(out_feat + (size_t)u * 128 + c4));
}

// ---------------------------------------------------------------- launch
extern "C" void kernel_launch(void* const* d_in, const int* in_sizes, int n_in,
                              void* d_out, int out_size, void* d_ws, size_t ws_size,
                              hipStream_t stream) {
    const int*   a_loc  = (const int*)  d_in[0];
    const float* a_feat = (const float*)d_in[1];
    const int*   b_loc  = (const int*)  d_in[2];
    const float* b_feat = (const float*)d_in[3];

    const int Na = in_sizes[0] / 3;
    const int Nb = in_sizes[2] / 3;
    const int N  = Na + Nb;                      // 400000

    float* out_loc  = (float*)d_out;             // N*3 floats (unique_locations, -1 padded)
    float* out_feat = out_loc + (size_t)N * 3;   // N*128 floats

    k_init<<<(N * 3 + TPB - 1) / TPB, TPB, 0, stream>>>(out_loc, N);
    k_mark<<<(N + TPB - 1) / TPB, TPB, 0, stream>>>(a_loc, b_loc, Na, N);
    k_scan_fused<<<SCAN_BLOCKS, TPB, 0, stream>>>(out_loc);
    k_reverse<<<(N + TPB - 1) / TPB, TPB, 0, stream>>>(a_loc, b_loc, Na, N);
    k_gather<<<(N * 32 + TPB - 1) / TPB, TPB, 0, stream>>>(a_feat, b_feat, out_feat, N);
}

// Round 5
// 153.141 us; speedup vs baseline: 1.8621x; 1.8621x over previous
//
#include <hip/hip_runtime.h>
#include <hip/hip_bf16.h>

// Problem constants (fixed by setup_inputs): Na=Nb=200000, Da=Db=64, S=256.
#define NKEYS   (1 << 24)          // 256^3 possible locations
#define NW      (NKEYS / 32)       // 524288 32-bit presence words (2 MB)
#define TPB     256
#define NBLK    512                // NW / (TPB*4) blocks in the scan passes
#define MAXN    400000             // Na + Nb

typedef float        f32x4 __attribute__((ext_vector_type(4)));
typedef unsigned int u32x4 __attribute__((ext_vector_type(4)));

// Device-global scratch. Re-initialized every call (deterministic).
__device__ unsigned int g_bits[NW];        // presence bitmask per key
__device__ unsigned int g_wordPrefix[NW];  // exclusive rank base per 32-key word
__device__ unsigned int g_blockSums[NBLK]; // per-block popcount -> exclusive base
__device__ unsigned int g_doneCounter;
__device__ int          g_winner_a[MAXN];  // per-unique-slot winning a-row (max index)
__device__ int          g_winner_b[MAXN];  // per-unique-slot winning b-row (max index)

// ---------------------------------------------------------------- fused init
__global__ void k_init(float* out_loc, int N) {
    int i = blockIdx.x * blockDim.x + threadIdx.x;          // 3N threads
    if (i < NW / 4) reinterpret_cast<u32x4*>(g_bits)[i] = (u32x4)(0u);
    if (i < N) { g_winner_a[i] = -1; g_winner_b[i] = -1; }
    if (i < N * 3) out_loc[i] = -1.0f;                      // fill_value=-1 padding rows
    if (i == 0) g_doneCounter = 0u;
}

// ---------------------------------------------------------------- mark presence (4 rows / thread)
__global__ void k_mark4(const int* __restrict__ a_loc, const int* __restrict__ b_loc,
                        int nA4, int n4) {
    int j = blockIdx.x * blockDim.x + threadIdx.x;          // N/4 threads
    if (j >= n4) return;
    const uint4* src = (j < nA4) ? reinterpret_cast<const uint4*>(a_loc)
                                 : reinterpret_cast<const uint4*>(b_loc);
    int jj = (j < nA4) ? j : j - nA4;
    uint4 q0 = src[jj * 3], q1 = src[jj * 3 + 1], q2 = src[jj * 3 + 2];
    int k0 = (q0.x << 16) | (q0.y << 8) | q0.z;
    int k1 = (q0.w << 16) | (q1.x << 8) | q1.y;
    int k2 = (q1.z << 16) | (q1.w << 8) | q2.x;
    int k3 = (q2.y << 16) | (q2.z << 8) | q2.w;
    atomicOr(&g_bits[k0 >> 5], 1u << (k0 & 31));
    atomicOr(&g_bits[k1 >> 5], 1u << (k1 & 31));
    atomicOr(&g_bits[k2 >> 5], 1u << (k2 & 31));
    atomicOr(&g_bits[k3 >> 5], 1u << (k3 & 31));
}

// ---------------------------------------------------------------- reduce + scan (last-block-done)
// Each block popcounts its 1024 words; the LAST block to finish scans the 512
// block sums in place (one agent fence per block, no spinning).
__global__ void k_reduce_scan() {
    __shared__ unsigned int s[TPB];
    __shared__ unsigned int isLast;
    int b = blockIdx.x, t = threadIdx.x;
    u32x4 w = reinterpret_cast<const u32x4*>(g_bits)[b * TPB + t];
    s[t] = __popc(w.x) + __popc(w.y) + __popc(w.z) + __popc(w.w);
    __syncthreads();
    for (int off = TPB / 2; off > 0; off >>= 1) {
        if (t < off) s[t] += s[t + off];
        __syncthreads();
    }
    if (t == 0) {
        g_blockSums[b] = s[0];
        __threadfence();                                    // publish sum (agent scope)
        unsigned int done = atomicAdd(&g_doneCounter, 1u);
        isLast = (done == NBLK - 1) ? 1u : 0u;
    }
    __syncthreads();
    if (isLast) {
        __threadfence();                                    // acquire all blocks' sums
        unsigned int v0 = g_blockSums[t * 2], v1 = g_blockSums[t * 2 + 1];
        unsigned int pair = v0 + v1;
        s[t] = pair;
        __syncthreads();
        for (int off = 1; off < TPB; off <<= 1) {
            unsigned int u = (t >= off) ? s[t - off] : 0u;
            __syncthreads();
            s[t] += u;
            __syncthreads();
        }
        unsigned int excl = s[t] - pair;                    // exclusive base
        g_blockSums[t * 2]     = excl;
        g_blockSums[t * 2 + 1] = excl + v0;
    }
}

// ---------------------------------------------------------------- word prefixes + sorted unique locations
__global__ void k_prefix_loc(float* __restrict__ out_loc) {
    __shared__ unsigned int s[TPB];
    int b = blockIdx.x, t = threadIdx.x;
    int w0 = (b * TPB + t) * 4;
    u32x4 wv = reinterpret_cast<const u32x4*>(g_bits)[b * TPB + t];
    unsigned int wlocal[4] = { wv.x, wv.y, wv.z, wv.w };
    unsigned int cnt = __popc(wv.x) + __popc(wv.y) + __popc(wv.z) + __popc(wv.w);
    s[t] = cnt;
    __syncthreads();
    for (int off = 1; off < TPB; off <<= 1) {
        unsigned int u = (t >= off) ? s[t - off] : 0u;
        __syncthreads();
        s[t] += u;
        __syncthreads();
    }
    unsigned int r = g_blockSums[b] + s[t] - cnt;           // exclusive rank base
#pragma unroll
    for (int j = 0; j < 4; ++j) {
        unsigned int bits = wlocal[j];
        g_wordPrefix[w0 + j] = r;
        while (bits) {
            int bit = __ffs(bits) - 1;
            bits &= bits - 1;
            int key = ((w0 + j) << 5) | bit;
            float* p = out_loc + (size_t)r * 3;
            p[0] = (float)(key >> 16);
            p[1] = (float)((key >> 8) & 255);
            p[2] = (float)(key & 255);
            ++r;
        }
    }
}

// ---------------------------------------------------------------- inverse + winners (4 rows / thread)
__global__ void k_reverse4(const int* __restrict__ a_loc, const int* __restrict__ b_loc,
                           int nA4, int n4) {
    int j = blockIdx.x * blockDim.x + threadIdx.x;          // N/4 threads
    if (j >= n4) return;
    bool isA = (j < nA4);
    const uint4* src = isA ? reinterpret_cast<const uint4*>(a_loc)
                           : reinterpret_cast<const uint4*>(b_loc);
    int jj = isA ? j : j - nA4;
    uint4 q0 = src[jj * 3], q1 = src[jj * 3 + 1], q2 = src[jj * 3 + 2];
    int key[4];
    key[0] = (q0.x << 16) | (q0.y << 8) | q0.z;
    key[1] = (q0.w << 16) | (q1.x << 8) | q1.y;
    key[2] = (q1.z << 16) | (q1.w << 8) | q2.x;
    key[3] = (q2.y << 16) | (q2.z << 8) | q2.w;
    int* winner = isA ? g_winner_a : g_winner_b;
    int base = jj * 4;
#pragma unroll
    for (int k = 0; k < 4; ++k) {
        int kk = key[k];
        unsigned int word = g_bits[kk >> 5];
        unsigned int r = g_wordPrefix[kk >> 5] + __popc(word & ((1u << (kk & 31)) - 1u));
        atomicMax(&winner[r], base + k);                    // last (max) row index wins (XLA order)
    }
}

// scalar fallbacks (only used if Na or Nb not divisible by 4)
__global__ void k_mark1(const int* __restrict__ a_loc, const int* __restrict__ b_loc,
                        int Na, int N) {
    int i = blockIdx.x * blockDim.x + threadIdx.x;
    if (i >= N) return;
    const int* p = (i < Na) ? (a_loc + (size_t)i * 3) : (b_loc + (size_t)(i - Na) * 3);
    int key = (p[0] << 16) | (p[1] << 8) | p[2];
    atomicOr(&g_bits[key >> 5], 1u << (key & 31));
}
__global__ void k_reverse1(const int* __restrict__ a_loc, const int* __restrict__ b_loc,
                           int Na, int N) {
    int i = blockIdx.x * blockDim.x + threadIdx.x;
    if (i >= N) return;
    const int* p = (i < Na) ? (a_loc + (size_t)i * 3) : (b_loc + (size_t)(i - Na) * 3);
    int key = (p[0] << 16) | (p[1] << 8) | p[2];
    unsigned int word = g_bits[key >> 5];
    unsigned int r = g_wordPrefix[key >> 5] + __popc(word & ((1u << (key & 31)) - 1u));
    if (i < Na) atomicMax(&g_winner_a[r], i);
    else        atomicMax(&g_winner_b[r], i - Na);
}

// ---------------------------------------------------------------- gather features (nt: use-once streams)
__global__ void k_gather(const float* __restrict__ a_feat, const float* __restrict__ b_feat,
                         float* __restrict__ out_feat, int N) {
    int idx = blockIdx.x * blockDim.x + threadIdx.x;        // N*32 threads, float4 each
    if (idx >= N * 32) return;
    int u  = idx >> 5;
    int c4 = (idx & 31) * 4;
    f32x4 v = (f32x4)(0.f);
    if (c4 < 64) {
        int w = g_winner_a[u];
        if (w >= 0) v = __builtin_nontemporal_load(
                            reinterpret_cast<const f32x4*>(a_feat + (size_t)w * 64 + c4));
    } else {
        int w = g_winner_b[u];
        if (w >= 0) v = __builtin_nontemporal_load(
                            reinterpret_cast<const f32x4*>(b_feat + (size_t)w * 64 + (c4 - 64)));
    }
    __builtin_nontemporal_store(v, reinterpret_cast<f32x4*>(out_feat + (size_t)u * 128 + c4));
}

// ---------------------------------------------------------------- launch
extern "C" void kernel_launch(void* const* d_in, const int* in_sizes, int n_in,
                              void* d_out, int out_size, void* d_ws, size_t ws_size,
                              hipStream_t stream) {
    const int*   a_loc  = (const int*)  d_in[0];
    const float* a_feat = (const float*)d_in[1];
    const int*   b_loc  = (const int*)  d_in[2];
    const float* b_feat = (const float*)d_in[3];

    const int Na = in_sizes[0] / 3;
    const int Nb = in_sizes[2] / 3;
    const int N  = Na + Nb;                      // 400000

    float* out_loc  = (float*)d_out;             // N*3 floats (unique_locations, -1 padded)
    float* out_feat = out_loc + (size_t)N * 3;   // N*128 floats

    k_init<<<(N * 3 + TPB - 1) / TPB, TPB, 0, stream>>>(out_loc, N);

    if ((Na % 4) == 0 && (Nb % 4) == 0) {
        int nA4 = Na / 4, n4 = (Na + Nb) / 4;
        k_mark4<<<(n4 + TPB - 1) / TPB, TPB, 0, stream>>>(a_loc, b_loc, nA4, n4);
        k_reduce_scan<<<NBLK, TPB, 0, stream>>>();
        k_prefix_loc<<<NBLK, TPB, 0, stream>>>(out_loc);
        k_reverse4<<<(n4 + TPB - 1) / TPB, TPB, 0, stream>>>(a_loc, b_loc, nA4, n4);
    } else {
        k_mark1<<<(N + TPB - 1) / TPB, TPB, 0, stream>>>(a_loc, b_loc, Na, N);
        k_reduce_scan<<<NBLK, TPB, 0, stream>>>();
        k_prefix_loc<<<NBLK, TPB, 0, stream>>>(out_loc);
        k_reverse1<<<(N + TPB - 1) / TPB, TPB, 0, stream>>>(a_loc, b_loc, Na, N);
    }

    k_gather<<<(N * 32 + TPB - 1) / TPB, TPB, 0, stream>>>(a_feat, b_feat, out_feat, N);
}